// Round 10
// baseline (322.481 us; speedup 1.0000x reference)
//
#include <hip/hip_runtime.h>

#define D 128
#define BW_LOG 6          // 64 nodes per bucket
#define BWID 64
#define CAP 4096          // max edges per bucket in LDS (mean ~2048, max ~2350)
#define CHUNK 4096        // edges per partition block (391 blocks -> occupancy)
#define NB_MAX 1024       // supports N <= 65536 (also required by 16-bit src packing)
#define NSLAB 4           // x-table slabs for L2-resident gather phases
#define NPB 98            // nodes per aggregate block (511 blocks, all co-resident)

typedef unsigned short u16;
typedef unsigned int u32;
typedef __attribute__((ext_vector_type(8))) short bf16x8;      // 8 bf16 (4 VGPRs)
typedef __attribute__((ext_vector_type(8))) unsigned short u16x8;
typedef __attribute__((ext_vector_type(4))) float f32x4;

__device__ __forceinline__ float bf2f(u16 h) { return __uint_as_float(((u32)h) << 16); }
__device__ __forceinline__ u16 f2bf(float f) {
    u32 u = __float_as_uint(f);
    u32 r = (u + 0x7fffu + ((u >> 16) & 1u)) >> 16;   // RNE
    return (u16)r;
}

// ---------- dtype conversion ----------

__global__ __launch_bounds__(256)
void cvt_x_kernel(const float* __restrict__ x, u16* __restrict__ xb, int n4) {
    int i = blockIdx.x * 256 + threadIdx.x;
    if (i < n4) {
        float4 v = ((const float4*)x)[i];
        ushort4 o;
        o.x = f2bf(v.x); o.y = f2bf(v.y); o.z = f2bf(v.z); o.w = f2bf(v.w);
        ((ushort4*)xb)[i] = o;
    }
}

// both layers' wcat in one launch: blocks 0..127 -> wc1 row n, 128..255 -> wc2 row n-128
__global__ __launch_bounds__(256)
void cvt_w_kernel(const float* __restrict__ W1l, const float* __restrict__ W1r,
                  const float* __restrict__ W2l, const float* __restrict__ W2r,
                  u16* __restrict__ wc1, u16* __restrict__ wc2) {
    int b = blockIdx.x, k = threadIdx.x;
    int n = b & 127;
    const float* Wl = (b < 128) ? W1l : W2l;
    const float* Wr = (b < 128) ? W1r : W2r;
    u16* wcat = (b < 128) ? wc1 : wc2;
    float v = (k < 128) ? Wl[n * 128 + k] : Wr[n * 128 + k - 128];
    wcat[n * 256 + k] = f2bf(v);
}

// ---------- CSR build via deterministic two-pass privatized counting sort ----------

__global__ __launch_bounds__(256)
void part_hist_kernel(const int* __restrict__ dst, int* __restrict__ gh,
                      int E, int nb, int nblk) {
    __shared__ int h[NB_MAX];
    int b = blockIdx.x;
    for (int i = threadIdx.x; i < nb; i += 256) h[i] = 0;
    __syncthreads();
    int lo = b * CHUNK, hi = min(lo + CHUNK, E);
    for (int i = lo + threadIdx.x; i < hi; i += 256) atomicAdd(&h[dst[i] >> BW_LOG], 1);
    __syncthreads();
    for (int i = threadIdx.x; i < nb; i += 256) gh[(size_t)i * nblk + b] = h[i];
}

__global__ __launch_bounds__(64)
void part_scan1_kernel(int* __restrict__ gh, int* __restrict__ btot, int nblk) {
    int k = blockIdx.x;
    int t = threadIdx.x;
    int* row = gh + (size_t)k * nblk;
    int chunk = (nblk + 63) >> 6;
    int lo = t * chunk, hi = min(lo + chunk, nblk);
    int s = 0;
    for (int i = lo; i < hi; ++i) s += row[i];
    int incl = s;
#pragma unroll
    for (int d2 = 1; d2 < 64; d2 <<= 1) { int u = __shfl_up(incl, d2, 64); if (t >= d2) incl += u; }
    int excl = incl - s;
    for (int i = lo; i < hi; ++i) { int c = row[i]; row[i] = excl; excl += c; }
    if (t == 63) btot[k] = incl;
}

__global__ __launch_bounds__(1024)
void part_scan2_kernel(const int* __restrict__ btot, int* __restrict__ bbase,
                       int nb, int* __restrict__ offN) {
    __shared__ int ws[16];
    int t = threadIdx.x, lane = t & 63, wid = t >> 6;
    int v = (t < nb) ? btot[t] : 0;
    int incl = v;
#pragma unroll
    for (int d2 = 1; d2 < 64; d2 <<= 1) { int u = __shfl_up(incl, d2, 64); if (lane >= d2) incl += u; }
    if (lane == 63) ws[wid] = incl;
    __syncthreads();
    if (wid == 0) {
        int w = (lane < 16) ? ws[lane] : 0;
#pragma unroll
        for (int d2 = 1; d2 < 16; d2 <<= 1) { int u = __shfl_up(w, d2, 64); if (lane >= d2) w += u; }
        if (lane < 16) ws[lane] = w;
    }
    __syncthreads();
    int base = wid ? ws[wid - 1] : 0;
    int excl = base + incl - v;
    if (t < nb) bbase[t] = excl;
    if (t == nb - 1) { bbase[nb] = excl + v; *offN = excl + v; }
}

// record = (dst_local << 16) | src   (src < 65536)
__global__ __launch_bounds__(256)
void part_scatter_kernel(const int* __restrict__ src, const int* __restrict__ dst,
                         const int* __restrict__ gh, const int* __restrict__ bbase,
                         u32* __restrict__ ebuf, int E, int nb, int nblk) {
    __shared__ int cur[NB_MAX];
    int b = blockIdx.x;
    for (int i = threadIdx.x; i < nb; i += 256)
        cur[i] = bbase[i] + gh[(size_t)i * nblk + b];
    __syncthreads();
    int lo = b * CHUNK, hi = min(lo + CHUNK, E);
    for (int i = lo + threadIdx.x; i < hi; i += 256) {
        int d = dst[i];
        int p = atomicAdd(&cur[d >> BW_LOG], 1);
        ebuf[p] = ((u32)(d & (BWID - 1)) << 16) | (u32)src[i];
    }
}

// one block per bucket: LDS counting sort by (dst_local, slab(src)); key = dl*4+slab.
// Emits off2[node*4+slab] segment starts (globally consistent prefix) and src-sorted ebuf.
__global__ __launch_bounds__(256)
void bucket_sort_kernel(u32* __restrict__ ebuf, const int* __restrict__ bbase,
                        int* __restrict__ off2, int n_nodes, int sw) {
    __shared__ u32 in_s[CAP];
    __shared__ u16 out_s[CAP];
    __shared__ int hist[BWID * NSLAB], cur[BWID * NSLAB];
    __shared__ int wsum[4];
    int b = blockIdx.x;
    int base = bbase[b];
    int n_b = bbase[b + 1] - base;
    int t = threadIdx.x;
    hist[t] = 0;
    for (int i = t; i < n_b && i < CAP; i += 256) in_s[i] = ebuf[base + i];
    __syncthreads();
    for (int i = t; i < n_b && i < CAP; i += 256) {
        u32 v = in_s[i];
        int key = (int)(v >> 16) * NSLAB + (int)((v & 0xffffu) / (u32)sw);
        atomicAdd(&hist[key], 1);
    }
    __syncthreads();
    {
        int sv = hist[t];
        int lane = t & 63, w = t >> 6;
        int incl = sv;
#pragma unroll
        for (int d2 = 1; d2 < 64; d2 <<= 1) { int u = __shfl_up(incl, d2, 64); if (lane >= d2) incl += u; }
        if (lane == 63) wsum[w] = incl;
        __syncthreads();
        int wb = 0;
        for (int i = 0; i < 4; ++i) if (i < w) wb += wsum[i];
        int excl = wb + incl - sv;
        cur[t] = excl;
        int node = (b << BW_LOG) + (t >> 2);   // t = dl*4 + slab
        off2[(size_t)node * NSLAB + (t & 3)] = base + excl;
    }
    __syncthreads();
    for (int i = t; i < n_b && i < CAP; i += 256) {
        u32 v = in_s[i];
        int key = (int)(v >> 16) * NSLAB + (int)((v & 0xffffu) / (u32)sw);
        int p = atomicAdd(&cur[key], 1);
        if (p < CAP) out_s[p] = (u16)(v & 0xffffu);
    }
    __syncthreads();
    for (int i = t; i < n_b && i < CAP; i += 256) ebuf[base + i] = (u32)out_s[i];
}

// ---------- slab-phased mean aggregation ----------
// 511 blocks x 98 nodes, 512 threads (16 groups of 32 lanes), all blocks co-resident
// (52KB LDS -> 2 blocks/CU). Slab loop OUTERMOST: whole GPU gathers from one
// 3.2MB x-slab at a time -> per-XCD L2-resident phase. f32 partials in LDS,
// group owns its rows (no atomics, no barriers). Inner gather = R5-measured shape.

__global__ __launch_bounds__(512)
void aggregate_slab_kernel(const u16* __restrict__ xb, const int* __restrict__ off2,
                           const u32* __restrict__ eidx, u16* __restrict__ meanb,
                           int n_nodes) {
    __shared__ float acc_s[NPB * 132];
    int t = threadIdx.x;
    int g = t >> 5;            // group 0..15
    int lane = t & 31;
    int c = lane * 4;
    int n0 = blockIdx.x * NPB;

    for (int nl = g; nl < NPB; nl += 16)
        *(float4*)&acc_s[nl * 132 + c] = make_float4(0.f, 0.f, 0.f, 0.f);
    // no barrier needed: each group touches only rows nl == g (mod 16)

    for (int s = 0; s < NSLAB; ++s) {
        for (int nl = g; nl < NPB; nl += 16) {
            int n = n0 + nl;
            if (n >= n_nodes) break;
            int beg = off2[(size_t)n * NSLAB + s];
            int end = off2[(size_t)n * NSLAB + s + 1];
            if (beg == end) continue;
            float ax = 0.f, ay = 0.f, az = 0.f, aw = 0.f;
            int e = beg;
            for (; e + 8 <= end; e += 8) {
                ushort4 v0 = *(const ushort4*)&xb[(size_t)eidx[e + 0] * D + c];
                ushort4 v1 = *(const ushort4*)&xb[(size_t)eidx[e + 1] * D + c];
                ushort4 v2 = *(const ushort4*)&xb[(size_t)eidx[e + 2] * D + c];
                ushort4 v3 = *(const ushort4*)&xb[(size_t)eidx[e + 3] * D + c];
                ushort4 v4 = *(const ushort4*)&xb[(size_t)eidx[e + 4] * D + c];
                ushort4 v5 = *(const ushort4*)&xb[(size_t)eidx[e + 5] * D + c];
                ushort4 v6 = *(const ushort4*)&xb[(size_t)eidx[e + 6] * D + c];
                ushort4 v7 = *(const ushort4*)&xb[(size_t)eidx[e + 7] * D + c];
                ax += bf2f(v0.x) + bf2f(v1.x) + bf2f(v2.x) + bf2f(v3.x)
                    + bf2f(v4.x) + bf2f(v5.x) + bf2f(v6.x) + bf2f(v7.x);
                ay += bf2f(v0.y) + bf2f(v1.y) + bf2f(v2.y) + bf2f(v3.y)
                    + bf2f(v4.y) + bf2f(v5.y) + bf2f(v6.y) + bf2f(v7.y);
                az += bf2f(v0.z) + bf2f(v1.z) + bf2f(v2.z) + bf2f(v3.z)
                    + bf2f(v4.z) + bf2f(v5.z) + bf2f(v6.z) + bf2f(v7.z);
                aw += bf2f(v0.w) + bf2f(v1.w) + bf2f(v2.w) + bf2f(v3.w)
                    + bf2f(v4.w) + bf2f(v5.w) + bf2f(v6.w) + bf2f(v7.w);
            }
            for (; e < end; ++e) {
                ushort4 v = *(const ushort4*)&xb[(size_t)eidx[e] * D + c];
                ax += bf2f(v.x); ay += bf2f(v.y); az += bf2f(v.z); aw += bf2f(v.w);
            }
            float4 a4 = *(float4*)&acc_s[nl * 132 + c];
            a4.x += ax; a4.y += ay; a4.z += az; a4.w += aw;
            *(float4*)&acc_s[nl * 132 + c] = a4;
        }
    }

    for (int nl = g; nl < NPB; nl += 16) {
        int n = n0 + nl;
        if (n >= n_nodes) break;
        int deg = off2[(size_t)(n + 1) * NSLAB] - off2[(size_t)n * NSLAB];
        float inv = 1.f / (float)(deg > 0 ? deg : 1);
        float4 a4 = *(float4*)&acc_s[nl * 132 + c];
        ushort4 o;
        o.x = f2bf(a4.x * inv); o.y = f2bf(a4.y * inv);
        o.z = f2bf(a4.z * inv); o.w = f2bf(a4.w * inv);
        *(ushort4*)&meanb[(size_t)n * D + c] = o;
    }
}

// ---------- linear via MFMA with LDS-staged W ----------
// out = relu([mean||self] @ Wcat^T + b). Block = 64 rows (4 waves x 16-row tiles).
// Wcat (128x256 bf16) staged in LDS in two 32KB k-halves.
// mfma_f32_16x16x32_bf16: A row=l&15, k=(l>>4)*8+j ; C/D col=l&15, row=(l>>4)*4+reg.

template<bool OUT_BF16>
__global__ __launch_bounds__(256)
void linear_mfma_kernel(const u16* __restrict__ Amean, const u16* __restrict__ Aself,
                        const u16* __restrict__ Wc, const float* __restrict__ bias,
                        void* __restrict__ outp, int N) {
    __shared__ u16 ws[128][136];   // 34816 B

    int t = threadIdx.x;
    int l = t & 63;
    int wv = t >> 6;
    int m0 = blockIdx.x * 64 + wv * 16;
    int lr = l & 15;
    int kg = (l >> 4) * 8;
    int rowA = m0 + lr;
    int rc = rowA < N ? rowA : N - 1;
    const u16* r1 = Amean + (size_t)rc * D;
    const u16* r2 = Aself + (size_t)rc * D;

    bf16x8 a[8];
#pragma unroll
    for (int kt = 0; kt < 4; ++kt) {
        a[kt]     = *(const bf16x8*)(r1 + kt * 32 + kg);   // k 0..127  (mean)
        a[kt + 4] = *(const bf16x8*)(r2 + kt * 32 + kg);   // k 128..255 (self)
    }

    f32x4 acc[8];
#pragma unroll
    for (int nt = 0; nt < 8; ++nt) acc[nt] = (f32x4){0.f, 0.f, 0.f, 0.f};

    for (int half = 0; half < 2; ++half) {
        if (half) __syncthreads();         // all reads of previous half done
        // stage 128x128 bf16 k-half of Wcat: 2048 x 16B, 8 per thread
        for (int i = t; i < 2048; i += 256) {
            int n = i >> 4, kq = i & 15;
            *(u16x8*)&ws[n][kq * 8] = *(const u16x8*)&Wc[(size_t)n * 256 + half * 128 + kq * 8];
        }
        __syncthreads();

#pragma unroll
        for (int nt = 0; nt < 8; ++nt) {
            bf16x8 b0 = *(const bf16x8*)&ws[nt * 16 + lr][0 * 32 + kg];
            bf16x8 b1 = *(const bf16x8*)&ws[nt * 16 + lr][1 * 32 + kg];
            bf16x8 b2 = *(const bf16x8*)&ws[nt * 16 + lr][2 * 32 + kg];
            bf16x8 b3 = *(const bf16x8*)&ws[nt * 16 + lr][3 * 32 + kg];
            acc[nt] = __builtin_amdgcn_mfma_f32_16x16x32_bf16(a[half * 4 + 0], b0, acc[nt], 0, 0, 0);
            acc[nt] = __builtin_amdgcn_mfma_f32_16x16x32_bf16(a[half * 4 + 1], b1, acc[nt], 0, 0, 0);
            acc[nt] = __builtin_amdgcn_mfma_f32_16x16x32_bf16(a[half * 4 + 2], b2, acc[nt], 0, 0, 0);
            acc[nt] = __builtin_amdgcn_mfma_f32_16x16x32_bf16(a[half * 4 + 3], b3, acc[nt], 0, 0, 0);
        }
    }

#pragma unroll
    for (int nt = 0; nt < 8; ++nt) {
        int col = nt * 16 + lr;
        float bb = bias[col];
#pragma unroll
        for (int j = 0; j < 4; ++j) {
            int r = m0 + (l >> 4) * 4 + j;
            if (r < N) {
                float v = fmaxf(acc[nt][j] + bb, 0.f);
                if (OUT_BF16) ((u16*)outp)[(size_t)r * D + col] = f2bf(v);
                else          ((float*)outp)[(size_t)r * D + col] = v;
            }
        }
    }
}

extern "C" void kernel_launch(void* const* d_in, const int* in_sizes, int n_in,
                              void* d_out, int out_size, void* d_ws, size_t ws_size,
                              hipStream_t stream) {
    const float* x   = (const float*)d_in[0];
    const int*   ei  = (const int*)d_in[1];
    const float* W1l = (const float*)d_in[2];
    const float* W1r = (const float*)d_in[3];
    const float* b1  = (const float*)d_in[4];
    const float* W2l = (const float*)d_in[5];
    const float* W2r = (const float*)d_in[6];
    const float* b2  = (const float*)d_in[7];
    float* out = (float*)d_out;

    const int N = in_sizes[0] / D;
    const int E = in_sizes[1] / 2;
    const int* src = ei;
    const int* dst = ei + E;
    const int NB = (N + BWID - 1) >> BW_LOG;       // 782 for N=50000 (<= NB_MAX)
    const int NBLK = (E + CHUNK - 1) / CHUNK;      // 391 for E=1.6M
    const int SW = (N + NSLAB - 1) / NSLAB;        // 12500: slab width (3.2MB bf16 rows)

    // workspace layout, 64B-aligned blocks
    char* wp_ = (char*)d_ws;
    auto alloc = [&](size_t bytes) { char* p = wp_; wp_ += (bytes + 63) & ~(size_t)63; return p; };
    int* off2_p  = (int*)alloc(((size_t)NB * BWID * NSLAB + 1) * 4);
    int* bbase_p = (int*)alloc((size_t)(NB + 1) * 4);
    int* btot_p  = (int*)alloc((size_t)NB * 4);
    int* gh_p    = (int*)alloc((size_t)NB * NBLK * 4);
    u32* ebuf_p  = (u32*)alloc((size_t)E * 4);
    u16* xb      = (u16*)alloc((size_t)N * D * 2);
    u16* meanb   = (u16*)alloc((size_t)N * D * 2);
    u16* h1b     = (u16*)alloc((size_t)N * D * 2);
    u16* wc1     = (u16*)alloc((size_t)128 * 256 * 2);
    u16* wc2     = (u16*)alloc((size_t)128 * 256 * 2);

    // conversions
    cvt_x_kernel<<<(N * D / 4 + 255) / 256, 256, 0, stream>>>(x, xb, N * D / 4);
    cvt_w_kernel<<<256, 256, 0, stream>>>(W1l, W1r, W2l, W2r, wc1, wc2);

    // CSR build (+ slab-segmented off2)
    part_hist_kernel<<<NBLK, 256, 0, stream>>>(dst, gh_p, E, NB, NBLK);
    part_scan1_kernel<<<NB, 64, 0, stream>>>(gh_p, btot_p, NBLK);
    part_scan2_kernel<<<1, 1024, 0, stream>>>(btot_p, bbase_p, NB, off2_p + (size_t)NB * BWID * NSLAB);
    part_scatter_kernel<<<NBLK, 256, 0, stream>>>(src, dst, gh_p, bbase_p, ebuf_p, E, NB, NBLK);
    bucket_sort_kernel<<<NB, 256, 0, stream>>>(ebuf_p, bbase_p, off2_p, N, SW);

    const int AGG_GRID = (N + NPB - 1) / NPB;      // 511

    // layer 1
    aggregate_slab_kernel<<<AGG_GRID, 512, 0, stream>>>(xb, off2_p, ebuf_p, meanb, N);
    linear_mfma_kernel<true><<<(N + 63) / 64, 256, 0, stream>>>(meanb, xb, wc1, b1, h1b, N);

    // layer 2
    aggregate_slab_kernel<<<AGG_GRID, 512, 0, stream>>>(h1b, off2_p, ebuf_p, meanb, N);
    linear_mfma_kernel<false><<<(N + 63) / 64, 256, 0, stream>>>(meanb, h1b, wc2, b2, out, N);
}

// Round 11
// 213.412 us; speedup vs baseline: 1.5111x; 1.5111x over previous
//
#include <hip/hip_runtime.h>

#define D 128
#define BW_LOG 6          // 64 nodes per bucket
#define BWID 64
#define CAP 4096          // max edges per bucket in LDS (mean ~2048, max ~2350)
#define CHUNK 4096        // edges per partition block (391 blocks -> occupancy)
#define NB_MAX 1024       // supports N <= 65536 (also required by 16-bit src packing)

typedef unsigned short u16;
typedef unsigned int u32;
typedef __attribute__((ext_vector_type(8))) short bf16x8;      // 8 bf16 (4 VGPRs)
typedef __attribute__((ext_vector_type(8))) unsigned short u16x8;
typedef __attribute__((ext_vector_type(4))) float f32x4;

__device__ __forceinline__ float bf2f(u16 h) { return __uint_as_float(((u32)h) << 16); }
__device__ __forceinline__ u16 f2bf(float f) {
    u32 u = __float_as_uint(f);
    u32 r = (u + 0x7fffu + ((u >> 16) & 1u)) >> 16;   // RNE
    return (u16)r;
}

// ---------- fused prep: cvt_x + cvt_w + part_hist in one block-partitioned launch ----------
// blocks [0,xblk): x->bf16 ; [xblk,xblk+256): W->bf16 wcat ; rest: per-chunk dst histogram.

__global__ __launch_bounds__(256)
void prep_kernel(const float* __restrict__ x, u16* __restrict__ xb, int n4,
                 const float* __restrict__ W1l, const float* __restrict__ W1r,
                 const float* __restrict__ W2l, const float* __restrict__ W2r,
                 u16* __restrict__ wc1, u16* __restrict__ wc2,
                 const int* __restrict__ dst, int* __restrict__ gh,
                 int E, int nb, int nblk, int xblk) {
    __shared__ int h[NB_MAX];
    int b = blockIdx.x;
    int t = threadIdx.x;
    if (b < xblk) {
        int i = b * 256 + t;
        if (i < n4) {
            float4 v = ((const float4*)x)[i];
            ushort4 o;
            o.x = f2bf(v.x); o.y = f2bf(v.y); o.z = f2bf(v.z); o.w = f2bf(v.w);
            ((ushort4*)xb)[i] = o;
        }
        return;
    }
    if (b < xblk + 256) {
        int wb = b - xblk;
        int n = wb & 127;
        const float* Wl = (wb < 128) ? W1l : W2l;
        const float* Wr = (wb < 128) ? W1r : W2r;
        u16* wcat = (wb < 128) ? wc1 : wc2;
        float v = (t < 128) ? Wl[n * 128 + t] : Wr[n * 128 + t - 128];
        wcat[n * 256 + t] = f2bf(v);
        return;
    }
    int hb = b - xblk - 256;
    for (int i = t; i < nb; i += 256) h[i] = 0;
    __syncthreads();
    int lo = hb * CHUNK, hi = min(lo + CHUNK, E);
    for (int i = lo + t; i < hi; i += 256) atomicAdd(&h[dst[i] >> BW_LOG], 1);
    __syncthreads();
    for (int i = t; i < nb; i += 256) gh[(size_t)i * nblk + hb] = h[i];
}

// ---------- CSR build: scans + privatized scatter + per-bucket LDS counting sort ----------

__global__ __launch_bounds__(64)
void part_scan1_kernel(int* __restrict__ gh, int* __restrict__ btot, int nblk) {
    int k = blockIdx.x;
    int t = threadIdx.x;
    int* row = gh + (size_t)k * nblk;
    int chunk = (nblk + 63) >> 6;
    int lo = t * chunk, hi = min(lo + chunk, nblk);
    int s = 0;
    for (int i = lo; i < hi; ++i) s += row[i];
    int incl = s;
#pragma unroll
    for (int d2 = 1; d2 < 64; d2 <<= 1) { int u = __shfl_up(incl, d2, 64); if (t >= d2) incl += u; }
    int excl = incl - s;
    for (int i = lo; i < hi; ++i) { int c = row[i]; row[i] = excl; excl += c; }
    if (t == 63) btot[k] = incl;
}

__global__ __launch_bounds__(1024)
void part_scan2_kernel(const int* __restrict__ btot, int* __restrict__ bbase,
                       int nb, int* __restrict__ offN) {
    __shared__ int ws[16];
    int t = threadIdx.x, lane = t & 63, wid = t >> 6;
    int v = (t < nb) ? btot[t] : 0;
    int incl = v;
#pragma unroll
    for (int d2 = 1; d2 < 64; d2 <<= 1) { int u = __shfl_up(incl, d2, 64); if (lane >= d2) incl += u; }
    if (lane == 63) ws[wid] = incl;
    __syncthreads();
    if (wid == 0) {
        int w = (lane < 16) ? ws[lane] : 0;
#pragma unroll
        for (int d2 = 1; d2 < 16; d2 <<= 1) { int u = __shfl_up(w, d2, 64); if (lane >= d2) w += u; }
        if (lane < 16) ws[lane] = w;
    }
    __syncthreads();
    int base = wid ? ws[wid - 1] : 0;
    int excl = base + incl - v;
    if (t < nb) bbase[t] = excl;
    if (t == nb - 1) { bbase[nb] = excl + v; *offN = excl + v; }
}

// record = (dst_local << 16) | src   (src < 65536)
__global__ __launch_bounds__(256)
void part_scatter_kernel(const int* __restrict__ src, const int* __restrict__ dst,
                         const int* __restrict__ gh, const int* __restrict__ bbase,
                         u32* __restrict__ ebuf, int E, int nb, int nblk) {
    __shared__ int cur[NB_MAX];
    int b = blockIdx.x;
    for (int i = threadIdx.x; i < nb; i += 256)
        cur[i] = bbase[i] + gh[(size_t)i * nblk + b];
    __syncthreads();
    int lo = b * CHUNK, hi = min(lo + CHUNK, E);
    for (int i = lo + threadIdx.x; i < hi; i += 256) {
        int d = dst[i];
        int p = atomicAdd(&cur[d >> BW_LOG], 1);
        ebuf[p] = ((u32)(d & (BWID - 1)) << 16) | (u32)src[i];
    }
}

__global__ __launch_bounds__(256)
void bucket_sort_kernel(u32* __restrict__ ebuf, const int* __restrict__ bbase,
                        int* __restrict__ off, int n_nodes) {
    __shared__ u32 in_s[CAP];
    __shared__ u16 out_s[CAP];
    __shared__ int hist[BWID], cur[BWID];
    int b = blockIdx.x;
    int base = bbase[b];
    int n_b = bbase[b + 1] - base;
    int t = threadIdx.x;
    if (t < BWID) hist[t] = 0;
    for (int i = t; i < n_b && i < CAP; i += 256) in_s[i] = ebuf[base + i];
    __syncthreads();
    for (int i = t; i < n_b && i < CAP; i += 256) atomicAdd(&hist[in_s[i] >> 16], 1);
    __syncthreads();
    if (t < BWID) {
        int s = hist[t];
        int incl = s;
#pragma unroll
        for (int d2 = 1; d2 < 64; d2 <<= 1) { int u = __shfl_up(incl, d2, 64); if (t >= d2) incl += u; }
        int excl = incl - s;
        cur[t] = excl;
        int node = (b << BW_LOG) + t;
        if (node < n_nodes) off[node] = base + excl;
    }
    __syncthreads();
    for (int i = t; i < n_b && i < CAP; i += 256) {
        u32 v = in_s[i];
        int p = atomicAdd(&cur[v >> 16], 1);
        if (p < CAP) out_s[p] = (u16)(v & 0xffffu);
    }
    __syncthreads();
    for (int i = t; i < n_b && i < CAP; i += 256) ebuf[base + i] = (u32)out_s[i];
}

// ---------- mean aggregation over bf16 rows ----------
// R5/R9-measured shape: 32 lanes/node (ushort4), 8 nodes/block, unroll x8.
// Fill-path-bound: dur ~= FETCH / 3.5 TB/s. Slab phasing (R10) cut FETCH 209->71MB
// but went latency-bound (114us) -- reverted.

__global__ __launch_bounds__(256)
void aggregate_bf16_kernel(const u16* __restrict__ xb, const int* __restrict__ off,
                           const u32* __restrict__ eidx, u16* __restrict__ meanb,
                           int n_nodes) {
    int node = blockIdx.x * 8 + (threadIdx.x >> 5);
    int lane = threadIdx.x & 31;
    if (node >= n_nodes) return;
    int beg = off[node], end = off[node + 1];
    int c = lane * 4;

    float ax = 0.f, ay = 0.f, az = 0.f, aw = 0.f;
    int e = beg;
    for (; e + 8 <= end; e += 8) {
        ushort4 v0 = *(const ushort4*)&xb[(size_t)eidx[e + 0] * D + c];
        ushort4 v1 = *(const ushort4*)&xb[(size_t)eidx[e + 1] * D + c];
        ushort4 v2 = *(const ushort4*)&xb[(size_t)eidx[e + 2] * D + c];
        ushort4 v3 = *(const ushort4*)&xb[(size_t)eidx[e + 3] * D + c];
        ushort4 v4 = *(const ushort4*)&xb[(size_t)eidx[e + 4] * D + c];
        ushort4 v5 = *(const ushort4*)&xb[(size_t)eidx[e + 5] * D + c];
        ushort4 v6 = *(const ushort4*)&xb[(size_t)eidx[e + 6] * D + c];
        ushort4 v7 = *(const ushort4*)&xb[(size_t)eidx[e + 7] * D + c];
        ax += bf2f(v0.x) + bf2f(v1.x) + bf2f(v2.x) + bf2f(v3.x)
            + bf2f(v4.x) + bf2f(v5.x) + bf2f(v6.x) + bf2f(v7.x);
        ay += bf2f(v0.y) + bf2f(v1.y) + bf2f(v2.y) + bf2f(v3.y)
            + bf2f(v4.y) + bf2f(v5.y) + bf2f(v6.y) + bf2f(v7.y);
        az += bf2f(v0.z) + bf2f(v1.z) + bf2f(v2.z) + bf2f(v3.z)
            + bf2f(v4.z) + bf2f(v5.z) + bf2f(v6.z) + bf2f(v7.z);
        aw += bf2f(v0.w) + bf2f(v1.w) + bf2f(v2.w) + bf2f(v3.w)
            + bf2f(v4.w) + bf2f(v5.w) + bf2f(v6.w) + bf2f(v7.w);
    }
    for (; e < end; ++e) {
        ushort4 v = *(const ushort4*)&xb[(size_t)eidx[e] * D + c];
        ax += bf2f(v.x); ay += bf2f(v.y); az += bf2f(v.z); aw += bf2f(v.w);
    }

    int deg = end - beg;
    float inv = 1.f / (float)(deg > 0 ? deg : 1);
    ushort4 o;
    o.x = f2bf(ax * inv); o.y = f2bf(ay * inv); o.z = f2bf(az * inv); o.w = f2bf(aw * inv);
    *(ushort4*)&meanb[(size_t)node * D + c] = o;
}

// ---------- linear via MFMA with LDS-staged W ----------
// out = relu([mean||self] @ Wcat^T + b). Block = 128 rows (8 waves x 16-row tiles),
// halving W-staging traffic vs 64-row blocks. Wcat staged in two 32KB k-halves.
// mfma_f32_16x16x32_bf16: A row=l&15, k=(l>>4)*8+j ; C/D col=l&15, row=(l>>4)*4+reg.

template<bool OUT_BF16>
__global__ __launch_bounds__(512)
void linear_mfma_kernel(const u16* __restrict__ Amean, const u16* __restrict__ Aself,
                        const u16* __restrict__ Wc, const float* __restrict__ bias,
                        void* __restrict__ outp, int N) {
    __shared__ u16 ws[128][136];   // 34816 B

    int t = threadIdx.x;
    int l = t & 63;
    int wv = t >> 6;               // 0..7
    int m0 = blockIdx.x * 128 + wv * 16;
    int lr = l & 15;
    int kg = (l >> 4) * 8;
    int rowA = m0 + lr;
    int rc = rowA < N ? rowA : N - 1;
    const u16* r1 = Amean + (size_t)rc * D;
    const u16* r2 = Aself + (size_t)rc * D;

    bf16x8 a[8];
#pragma unroll
    for (int kt = 0; kt < 4; ++kt) {
        a[kt]     = *(const bf16x8*)(r1 + kt * 32 + kg);   // k 0..127  (mean)
        a[kt + 4] = *(const bf16x8*)(r2 + kt * 32 + kg);   // k 128..255 (self)
    }

    f32x4 acc[8];
#pragma unroll
    for (int nt = 0; nt < 8; ++nt) acc[nt] = (f32x4){0.f, 0.f, 0.f, 0.f};

    for (int half = 0; half < 2; ++half) {
        if (half) __syncthreads();         // all reads of previous half done
        // stage 128x128 bf16 k-half of Wcat: 2048 x 16B, 4 per thread
        for (int i = t; i < 2048; i += 512) {
            int n = i >> 4, kq = i & 15;
            *(u16x8*)&ws[n][kq * 8] = *(const u16x8*)&Wc[(size_t)n * 256 + half * 128 + kq * 8];
        }
        __syncthreads();

#pragma unroll
        for (int nt = 0; nt < 8; ++nt) {
            bf16x8 b0 = *(const bf16x8*)&ws[nt * 16 + lr][0 * 32 + kg];
            bf16x8 b1 = *(const bf16x8*)&ws[nt * 16 + lr][1 * 32 + kg];
            bf16x8 b2 = *(const bf16x8*)&ws[nt * 16 + lr][2 * 32 + kg];
            bf16x8 b3 = *(const bf16x8*)&ws[nt * 16 + lr][3 * 32 + kg];
            acc[nt] = __builtin_amdgcn_mfma_f32_16x16x32_bf16(a[half * 4 + 0], b0, acc[nt], 0, 0, 0);
            acc[nt] = __builtin_amdgcn_mfma_f32_16x16x32_bf16(a[half * 4 + 1], b1, acc[nt], 0, 0, 0);
            acc[nt] = __builtin_amdgcn_mfma_f32_16x16x32_bf16(a[half * 4 + 2], b2, acc[nt], 0, 0, 0);
            acc[nt] = __builtin_amdgcn_mfma_f32_16x16x32_bf16(a[half * 4 + 3], b3, acc[nt], 0, 0, 0);
        }
    }

#pragma unroll
    for (int nt = 0; nt < 8; ++nt) {
        int col = nt * 16 + lr;
        float bb = bias[col];
#pragma unroll
        for (int j = 0; j < 4; ++j) {
            int r = m0 + (l >> 4) * 4 + j;
            if (r < N) {
                float v = fmaxf(acc[nt][j] + bb, 0.f);
                if (OUT_BF16) ((u16*)outp)[(size_t)r * D + col] = f2bf(v);
                else          ((float*)outp)[(size_t)r * D + col] = v;
            }
        }
    }
}

extern "C" void kernel_launch(void* const* d_in, const int* in_sizes, int n_in,
                              void* d_out, int out_size, void* d_ws, size_t ws_size,
                              hipStream_t stream) {
    const float* x   = (const float*)d_in[0];
    const int*   ei  = (const int*)d_in[1];
    const float* W1l = (const float*)d_in[2];
    const float* W1r = (const float*)d_in[3];
    const float* b1  = (const float*)d_in[4];
    const float* W2l = (const float*)d_in[5];
    const float* W2r = (const float*)d_in[6];
    const float* b2  = (const float*)d_in[7];
    float* out = (float*)d_out;

    const int N = in_sizes[0] / D;
    const int E = in_sizes[1] / 2;
    const int* src = ei;
    const int* dst = ei + E;
    const int NB = (N + BWID - 1) >> BW_LOG;       // 782 for N=50000 (<= NB_MAX)
    const int NBLK = (E + CHUNK - 1) / CHUNK;      // 391 for E=1.6M
    const int N4 = N * D / 4;
    const int XBLK = (N4 + 255) / 256;             // 6250

    // workspace layout, 64B-aligned blocks
    char* wp_ = (char*)d_ws;
    auto alloc = [&](size_t bytes) { char* p = wp_; wp_ += (bytes + 63) & ~(size_t)63; return p; };
    int* off_p   = (int*)alloc((size_t)(N + 1) * 4);
    int* bbase_p = (int*)alloc((size_t)(NB + 1) * 4);
    int* btot_p  = (int*)alloc((size_t)NB * 4);
    int* gh_p    = (int*)alloc((size_t)NB * NBLK * 4);
    u32* ebuf_p  = (u32*)alloc((size_t)E * 4);
    u16* xb      = (u16*)alloc((size_t)N * D * 2);
    u16* meanb   = (u16*)alloc((size_t)N * D * 2);
    u16* h1b     = (u16*)alloc((size_t)N * D * 2);
    u16* wc1     = (u16*)alloc((size_t)128 * 256 * 2);
    u16* wc2     = (u16*)alloc((size_t)128 * 256 * 2);

    // fused prep: cvt_x + cvt_w + part_hist
    prep_kernel<<<XBLK + 256 + NBLK, 256, 0, stream>>>(
        x, xb, N4, W1l, W1r, W2l, W2r, wc1, wc2, dst, gh_p, E, NB, NBLK, XBLK);

    // CSR build
    part_scan1_kernel<<<NB, 64, 0, stream>>>(gh_p, btot_p, NBLK);
    part_scan2_kernel<<<1, 1024, 0, stream>>>(btot_p, bbase_p, NB, off_p + N);
    part_scatter_kernel<<<NBLK, 256, 0, stream>>>(src, dst, gh_p, bbase_p, ebuf_p, E, NB, NBLK);
    bucket_sort_kernel<<<NB, 256, 0, stream>>>(ebuf_p, bbase_p, off_p, N);

    // layer 1
    aggregate_bf16_kernel<<<(N + 7) / 8, 256, 0, stream>>>(xb, off_p, ebuf_p, meanb, N);
    linear_mfma_kernel<true><<<(N + 127) / 128, 512, 0, stream>>>(meanb, xb, wc1, b1, h1b, N);

    // layer 2
    aggregate_bf16_kernel<<<(N + 7) / 8, 256, 0, stream>>>(h1b, off_p, ebuf_p, meanb, N);
    linear_mfma_kernel<false><<<(N + 127) / 128, 512, 0, stream>>>(meanb, h1b, wc2, b2, out, N);
}